// Round 5
// baseline (560.314 us; speedup 1.0000x reference)
//
#include <hip/hip_runtime.h>
#include <math.h>

#define HID 128
#define NSTEPS 64
#define SLEN 65
#define THREADS 512   // 8 waves/WG, 16 cols/wave
#define ROWS 32       // R17: 32 rows/WG -> per-wave A-tile halves -> R13 LDS totals
#define ASTRIDE 136   // 128 + 8 f16 pad, 16B aligned rows
#define FSTRIDE 40    // 32 + 8 f16 pad
#define DSTR 68       // 64 + 4 f32 pad, 16B-aligned rows for b128 flush reads

typedef _Float16 half8 __attribute__((ext_vector_type(8)));
typedef __fp16 fp16x2 __attribute__((ext_vector_type(2)));
typedef float floatx4 __attribute__((ext_vector_type(4)));

// R17 = R16 with ROWS 64->32: the occupancy experiment WITHOUT the LDS
// confound. R16 taught: A-broadcast LDS traffic scales with wave count
// (8 waves x full 64x128 A-tile = 2x bytes, conflicts 3.8e7->7.4e7, LDS
// pipe ~88% of wall -> 540us regression despite 38% occupancy). ROWS=32
// restores per-CU totals to R13 exactly (2WG x 8w x 8KB = 128KB/GEMM =
// R13's 2WG x 4w x 16KB) while keeping 16 waves/CU = 4 waves/SIMD (2x
// R13's latency-hiding). VGPR ~105-110 <= 128 cap of launch_bounds(512,4);
// R16 compiled spill-free at this cap with MORE live state (acc 16 vs 8).
// R13 features kept: weights-in-VGPR (zero LDS weight traffic), MFMA
// Wf-dot broadcast-B, zero global ops in k-loop, staged coalesced flush.
// CLOSED: 32-col/wave at any min-waves>2 (R15 spill: FETCH 3.2GB);
// ROWS=64 + 8 waves (R16: LDS traffic 2x); XOR swizzle (R14: conflict
// counter is structural b128 serialization, layout-invariant); residual-
// in-regs (R10/R11 spill); 32x32 MFMA; 6 barriers = dependency minimum.
// VGPR_Count CSV lies about spill - watch FETCH/WRITE_SIZE.
__global__ __launch_bounds__(THREADS, 4)
void hedger(const float* __restrict__ S,
            const float* __restrict__ W0,  const float* __restrict__ b0,
            const float* __restrict__ rW1, const float* __restrict__ rb1,
            const float* __restrict__ rW2, const float* __restrict__ rb2,
            const float* __restrict__ sW1, const float* __restrict__ sb1,
            const float* __restrict__ sW2, const float* __restrict__ sb2,
            const float* __restrict__ Wf,  const float* __restrict__ bfp,
            float* __restrict__ out)
{
  __shared__ __align__(16) _Float16 bufA[ROWS * ASTRIDE];   //  8704 B
  __shared__ __align__(16) _Float16 bufB[ROWS * ASTRIDE];   //  8704 B
  __shared__ __align__(16) _Float16 featb[ROWS * FSTRIDE];  //  2560 B
  __shared__ __align__(16) _Float16 WfS[HID];               //   256 B
  __shared__ __align__(16) _Float16 W0B[HID * 8];           //  2048 B  [col][j] = W0[j][col]
  __shared__ __align__(16) float    biasL[5 * HID];         //  2560 B  b0,rb1,rb2,sb1,sb2
  __shared__ __align__(16) float    Slds[ROWS * SLEN];      //  8320 B
  __shared__ __align__(16) float    deltab[ROWS * DSTR];    //  8704 B
  // total ~41.9 KB/WG -> 2 WGs/CU resident (VGPR-capped), LDS no limit

  const int tid  = threadIdx.x;
  const int wave = tid >> 6;            // 0..7
  const int lane = tid & 63;
  const int l15  = lane & 15;
  const int quad = lane >> 4;
  const int col  = wave * 16 + l15;     // lane's single output column
  const int r0   = blockIdx.x * ROWS;

  // ---- persistent B fragments (64 VGPR): k = quad*8 + j, n = col.
  half8 wfrag[4][4];  // [matrix][kIter]
  {
    const float* Wm[4] = {rW1, rW2, sW1, sW2};
#pragma unroll
    for (int m = 0; m < 4; ++m)
#pragma unroll
      for (int kq = 0; kq < 4; ++kq) {
        const int kb = kq * 32 + quad * 8;
        half8 f;
#pragma unroll
        for (int j = 0; j < 8; ++j)
          f[j] = (_Float16)Wm[m][(kb + j) * HID + col];
        wfrag[m][kq] = f;
      }
  }
  const float bfv = bfp[0];

  // LDS init: featb zero-fill (pad cols 8..31 stay zero), Wf, W0B (B-frag
  // friendly transpose: W0B[c*8+j] = W0[j][c]), biases, S staging.
  for (int i = tid; i < ROWS * FSTRIDE; i += THREADS) featb[i] = (_Float16)0.f;
  if (tid < HID) {
    WfS[tid] = (_Float16)Wf[tid];
#pragma unroll
    for (int j = 0; j < 8; ++j) W0B[tid * 8 + j] = (_Float16)W0[j * HID + tid];
    biasL[0 * HID + tid] = b0[tid];
    biasL[1 * HID + tid] = rb1[tid];
    biasL[2 * HID + tid] = rb2[tid];
    biasL[3 * HID + tid] = sb1[tid];
    biasL[4 * HID + tid] = sb2[tid];
  }
  for (int i = tid; i < ROWS * SLEN; i += THREADS)
    Slds[i] = S[(size_t)r0 * SLEN + i];       // contiguous, coalesced
  __syncthreads();   // init complete before feature writes

  // step-0 features (threads 0..31, one row each; S read from LDS)
  float lm_prev = 0.f, cum_x = 0.f, qv = 0.f;
  const float* Srow = &Slds[(tid & (ROWS - 1)) * SLEN];
  if (tid < ROWS) {
    const float lm = logf(Srow[0] * 0.01f);
    lm_prev = lm; cum_x = lm; qv = 0.f;
    _Float16* fr = &featb[tid * FSTRIDE];
    fr[0] = (_Float16)lm;
    fr[1] = (_Float16)1.0f;
    fr[2] = (_Float16)0.235f;
    fr[3] = (_Float16)0.f;                 // delta_0 = 0
    fr[4] = (_Float16)lm;                  // run_mean at k=0
    fr[5] = (_Float16)0.f;
    fr[6] = (_Float16)(1.9f * sqrtf(1e-12f));
    fr[7] = (_Float16)0.f;
  }
  __syncthreads();

  floatx4 acc[2];    // [mt]: rows mt*16 + quad*4 + r, col = col

#define INIT_BIAS(BI) do { \
  const float bv = biasL[(BI) * HID + col]; \
  _Pragma("unroll") for (int mt = 0; mt < 2; ++mt) { \
    floatx4 z = {bv, bv, bv, bv}; acc[mt] = z; } } while (0)

#define INIT_BIAS_RES(BI, RESBUF) do { \
  const float bv = biasL[(BI) * HID + col]; \
  _Pragma("unroll") for (int mt = 0; mt < 2; ++mt) \
  _Pragma("unroll") for (int r = 0; r < 4; ++r) { \
    const int row = mt * 16 + quad * 4 + r; \
    acc[mt][r] = bv + (float)RESBUF[row * ASTRIDE + col]; \
  } } while (0)

#define GEMM128(SRC, MI) do { \
  _Pragma("unroll") for (int kq = 0; kq < 4; ++kq) { \
    half8 afr[2]; \
    _Pragma("unroll") for (int mt = 0; mt < 2; ++mt) \
      afr[mt] = *(const half8*)&SRC[(mt * 16 + l15) * ASTRIDE + kq * 32 + quad * 8]; \
    _Pragma("unroll") for (int mt = 0; mt < 2; ++mt) \
      acc[mt] = __builtin_amdgcn_mfma_f32_16x16x32_f16( \
          afr[mt], wfrag[MI][kq], acc[mt], 0, 0, 0); \
  } } while (0)

// lrelu in f32, RTN casts, single b16 store per value (quad q hits banks
// 8q..8q+7 within its wave's 16-col slice)
#define EPI_LRELU(DST) do { \
  _Pragma("unroll") for (int mt = 0; mt < 2; ++mt) \
  _Pragma("unroll") for (int r = 0; r < 4; ++r) { \
    const int row = mt * 16 + quad * 4 + r; \
    const float v0 = acc[mt][r]; \
    DST[row * ASTRIDE + col] = (_Float16)fmaxf(v0, 0.2f * v0); \
  } } while (0)

#define EPI_STORE(DST) do { \
  _Pragma("unroll") for (int mt = 0; mt < 2; ++mt) \
  _Pragma("unroll") for (int r = 0; r < 4; ++r) { \
    const int row = mt * 16 + quad * 4 + r; \
    DST[row * ASTRIDE + col] = (_Float16)acc[mt][r]; \
  } } while (0)

#pragma unroll 1
  for (int k = 0; k < NSTEPS; ++k) {
    // G0: h0 = lrelu(featPad @ W0pad + b0). W0 B-frag from LDS (one b128,
    // quads 1..3 supply the K-pad zeros).
    INIT_BIAS(0);
    {
      half8 w0f;
      if (quad == 0) w0f = *(const half8*)&W0B[col * 8];
      else { half8 z = {0,0,0,0,0,0,0,0}; w0f = z; }
      half8 afr[2];
#pragma unroll
      for (int mt = 0; mt < 2; ++mt)
        afr[mt] = *(const half8*)&featb[(mt * 16 + l15) * FSTRIDE + quad * 8];
#pragma unroll
      for (int mt = 0; mt < 2; ++mt)
        acc[mt] = __builtin_amdgcn_mfma_f32_16x16x32_f16(
            afr[mt], w0f, acc[mt], 0, 0, 0);
    }
    EPI_LRELU(bufA);
    __syncthreads();                                   // bar A: bufA ready, featb consumed

    // delta-independent features of step k+1 — overlaps the GEMM phase.
    // (Slds[.. k+1] valid at k=63: SLEN=65; write is dead then, harmless.)
    if (tid < ROWS) {
      const int kk = k + 1;
      const float lm = logf(Srow[kk] * 0.01f);
      const float rr = lm - lm_prev; qv += rr * rr;
      lm_prev = lm; cum_x += lm;
      const float tT = (float)kk * (1.f / 64.f);
      _Float16* fr = &featb[tid * FSTRIDE];
      fr[0] = (_Float16)lm;
      fr[1] = (_Float16)(1.f - tT);
      fr[4] = (_Float16)(cum_x / (float)(kk + 1));
      fr[5] = (_Float16)qv;
      fr[6] = (_Float16)(1.9f * sqrtf(qv + 1e-12f));
      fr[7] = (_Float16)tT;
    }

    INIT_BIAS(1);               GEMM128(bufA, 0); EPI_LRELU(bufB);  // u
    __syncthreads();                                   // bar B
    INIT_BIAS_RES(2, bufA);     GEMM128(bufB, 1); EPI_STORE(bufA);  // h1
    __syncthreads();                                   // bar C
    INIT_BIAS(3);               GEMM128(bufA, 2); EPI_LRELU(bufB);  // v
    __syncthreads();                                   // bar D
    INIT_BIAS_RES(4, bufA);     GEMM128(bufB, 3); EPI_STORE(bufA);  // h2
    __syncthreads();                                   // bar E: h2 in bufA

    // delta = sigmoid(h2 @ Wf + bf) via MFMA with broadcast B (all cols =
    // Wf). Waves 0,1 cover the 32 rows (rows wave*16 + quad*4 + r).
    if (wave < 2) {
      floatx4 dacc = {0.f, 0.f, 0.f, 0.f};
#pragma unroll
      for (int kq = 0; kq < 4; ++kq) {
        const half8 a  = *(const half8*)&bufA[(wave * 16 + l15) * ASTRIDE + kq * 32 + quad * 8];
        const half8 wv = *(const half8*)&WfS[kq * 32 + quad * 8];   // broadcast read
        dacc = __builtin_amdgcn_mfma_f32_16x16x32_f16(a, wv, dacc, 0, 0, 0);
      }
      if (l15 < 4) {
        // static-index select of dacc[l15] (rule: no runtime vector index)
        const float sv = (l15 & 2) ? ((l15 & 1) ? dacc[3] : dacc[2])
                                   : ((l15 & 1) ? dacc[1] : dacc[0]);
        const int row = wave * 16 + quad * 4 + l15;
        const float d = 1.f / (1.f + expf(-(sv + bfv)));
        featb[row * FSTRIDE + 3] = (_Float16)d;        // fr[3] for step k+1
        deltab[row * DSTR + k] = d;                    // staged output
      }
    }
    __syncthreads();                                   // bar F: featb complete
  }

  // coalesced output flush: 32 rows x 64 steps, one dwordx4 per thread.
  // (bar F of k=63 made deltab fully visible.)
  {
    const int row = tid >> 4;                // 0..31
    const int c0  = (tid & 15) * 4;          // 0,4,...,60
    const floatx4 v = *(const floatx4*)&deltab[row * DSTR + c0];
    *(floatx4*)&out[(size_t)(r0 + row) * NSTEPS + c0] = v;
  }
#undef INIT_BIAS
#undef INIT_BIAS_RES
#undef GEMM128
#undef EPI_LRELU
#undef EPI_STORE
}

extern "C" void kernel_launch(void* const* d_in, const int* in_sizes, int n_in,
                              void* d_out, int out_size, void* d_ws, size_t ws_size,
                              hipStream_t stream) {
  const float* S   = (const float*)d_in[0];
  const float* W0  = (const float*)d_in[1];
  const float* b0  = (const float*)d_in[2];
  const float* rW1 = (const float*)d_in[3];
  const float* rb1 = (const float*)d_in[4];
  const float* rW2 = (const float*)d_in[5];
  const float* rb2 = (const float*)d_in[6];
  const float* sW1 = (const float*)d_in[7];
  const float* sb1 = (const float*)d_in[8];
  const float* sW2 = (const float*)d_in[9];
  const float* sb2 = (const float*)d_in[10];
  const float* Wf  = (const float*)d_in[11];
  const float* bf  = (const float*)d_in[12];
  float* out = (float*)d_out;

  const int B = out_size / NSTEPS;        // 32768
  const int nblocks = B / ROWS;           // 1024 WGs
  hedger<<<nblocks, THREADS, 0, stream>>>(
      S, W0, b0, rW1, rb1, rW2, rb2, sW1, sb1, sW2, sb2, Wf, bf, out);
}

// Round 6
// 429.070 us; speedup vs baseline: 1.3059x; 1.3059x over previous
//
#include <hip/hip_runtime.h>
#include <math.h>

#define HID 128
#define NSTEPS 64
#define SLEN 65
#define THREADS 256
#define ROWS 64
#define ASTRIDE 136   // 128 + 8 f16 pad, 16B aligned rows
#define FSTRIDE 40    // 32 + 8 f16 pad
#define DSTR 68       // 64 + 4 f32 pad, 16B-aligned rows for b128 flush reads

typedef _Float16 half8 __attribute__((ext_vector_type(8)));
typedef __fp16 fp16x2 __attribute__((ext_vector_type(2)));
typedef float floatx4 __attribute__((ext_vector_type(4)));

// R18 = R13 geometry (proven traffic-optimal) + G0 off the critical path.
// GEOMETRY LAW (R16/R17): LDS A-traffic per output elem = 1/(cols per wave);
// 16 cols/wave doubles LDS bytes regardless of tile rows (conflict counter
// 7.376e7 = 2x R13's 3.808e7 in BOTH R16 and R17). 32 cols/wave is max
// fitting registers (64 spills, R3) -> R13 geometry is the optimum. Closed.
// R18 CHANGE: delta enters G0 only as a rank-1 term (feat[3] x W0 row 3).
// So: pre_h0 = feat_{k+1}@W0Z + b0 (W0 row3 zeroed) is computed INSIDE the
// Wf phase (features k+1 stable since bar B; racing fr[3] writes are f16-
// atomic and multiply a zero weight -> contribute exactly 0). acc is dead
// during Wf -> holds pre_h0, +2 VGPR only (w03 pair). After bar F, G0
// collapses to rank-1: acc += delta[row]*W0[3,col] (16 broadcast u16 reads
// + 32 fma) + lrelu. Removes one latency-exposed GEMM phase from the serial
// 6-barrier chain; dacc/pre-h0 MFMA chains in Wf phase are independent and
// pipeline; sigmoid exp overlaps them.
// R13 kept: weights-in-VGPR, MFMA Wf-dot broadcast-B, zero global ops in
// k-loop (S in LDS, staged coalesced flush), 16-lane sigmoid.
// CLOSED: cols/wave != 32 (R3 spill / R16-R17 2x LDS); min-waves>2 (R15
// spill FETCH 3.2GB); XOR swizzle (R14: conflict counter structural,
// layout-invariant); residual-in-regs (R10/R11 spill); 32x32 MFMA;
// 6 barriers = dependency minimum. VGPR_Count CSV lies about spill —
// watch FETCH/WRITE_SIZE.
__global__ __launch_bounds__(THREADS, 2)
void hedger(const float* __restrict__ S,
            const float* __restrict__ W0,  const float* __restrict__ b0,
            const float* __restrict__ rW1, const float* __restrict__ rb1,
            const float* __restrict__ rW2, const float* __restrict__ rb2,
            const float* __restrict__ sW1, const float* __restrict__ sb1,
            const float* __restrict__ sW2, const float* __restrict__ sb2,
            const float* __restrict__ Wf,  const float* __restrict__ bfp,
            float* __restrict__ out)
{
  __shared__ __align__(16) _Float16 bufA[ROWS * ASTRIDE];
  __shared__ __align__(16) _Float16 bufB[ROWS * ASTRIDE];
  __shared__ __align__(16) _Float16 featb[ROWS * FSTRIDE];
  __shared__ __align__(16) _Float16 WfS[HID];
  __shared__ __align__(16) float    Slds[ROWS * SLEN];
  __shared__ __align__(16) float    deltab[ROWS * DSTR];

  const int tid  = threadIdx.x;
  const int wave = tid >> 6;            // 0..3
  const int lane = tid & 63;
  const int l15  = lane & 15;
  const int quad = lane >> 4;
  const int n_base = wave * 32;
  const int r0 = blockIdx.x * ROWS;
  const int col0 = n_base + 2 * l15;    // lane's adjacent column pair

  // ---- persistent B fragments (128 VGPR): n = col0 + nt, k = quad*8 + j.
  half8 wfrag[4][4][2];  // [matrix][kIter][nt]
  {
    const float* Wm[4] = {rW1, rW2, sW1, sW2};
#pragma unroll
    for (int m = 0; m < 4; ++m)
#pragma unroll
      for (int kq = 0; kq < 4; ++kq)
#pragma unroll
        for (int nt = 0; nt < 2; ++nt) {
          const int n  = col0 + nt;
          const int kb = kq * 32 + quad * 8;
          half8 f;
#pragma unroll
          for (int j = 0; j < 8; ++j)
            f[j] = (_Float16)Wm[m][(kb + j) * HID + n];
          wfrag[m][kq][nt] = f;
        }
  }
  // W0Z (8x128) zero-padded to K=32 AND row 3 zeroed (delta enters via
  // rank-1 update instead). Only quad 0 (k<8) is real.
  half8 w0fragZ[2];
#pragma unroll
  for (int nt = 0; nt < 2; ++nt) {
    const int n = col0 + nt;
    half8 f;
#pragma unroll
    for (int j = 0; j < 8; ++j) {
      const int k = quad * 8 + j;
      f[j] = (k < 8 && k != 3) ? (_Float16)W0[k * HID + n] : (_Float16)0.f;
    }
    w0fragZ[nt] = f;
  }
  // rank-1 weights: W0 row 3, f16-rounded to match the old MFMA operand.
  float w03[2];
#pragma unroll
  for (int nt = 0; nt < 2; ++nt)
    w03[nt] = (float)(_Float16)W0[3 * HID + col0 + nt];

  // biases for this lane's columns
  float b0r[2], rb1r[2], rb2r[2], sb1r[2], sb2r[2];
#pragma unroll
  for (int nt = 0; nt < 2; ++nt) {
    const int n = col0 + nt;
    b0r[nt] = b0[n]; rb1r[nt] = rb1[n]; rb2r[nt] = rb2[n];
    sb1r[nt] = sb1[n]; sb2r[nt] = sb2[n];
  }
  const float bfv = bfp[0];

  // LDS zero-fill (pad cols 8..31 stay zero forever) + Wf + S staging.
  for (int i = tid; i < ROWS * FSTRIDE; i += THREADS) featb[i] = (_Float16)0.f;
  if (tid < HID) WfS[tid] = (_Float16)Wf[tid];
  for (int i = tid; i < ROWS * SLEN; i += THREADS)
    Slds[i] = S[(size_t)r0 * SLEN + i];       // contiguous, coalesced
  __syncthreads();   // zero-fill + S staging complete before feature writes

  // step-0 features (threads 0..63 each own one row; S read from LDS)
  float lm_prev = 0.f, cum_x = 0.f, qv = 0.f;
  const float* Srow = &Slds[(tid & (ROWS - 1)) * SLEN];
  if (tid < ROWS) {
    const float lm = logf(Srow[0] * 0.01f);
    lm_prev = lm; cum_x = lm; qv = 0.f;
    _Float16* fr = &featb[tid * FSTRIDE];
    fr[0] = (_Float16)lm;
    fr[1] = (_Float16)1.0f;
    fr[2] = (_Float16)0.235f;
    fr[3] = (_Float16)0.f;                 // delta_0 = 0
    fr[4] = (_Float16)lm;                  // run_mean at k=0
    fr[5] = (_Float16)0.f;
    fr[6] = (_Float16)(1.9f * sqrtf(1e-12f));
    fr[7] = (_Float16)0.f;
  }
  __syncthreads();

  floatx4 acc[4][2];

#define INIT_BIAS(BR) do { \
  _Pragma("unroll") for (int mt = 0; mt < 4; ++mt) \
  _Pragma("unroll") for (int nt = 0; nt < 2; ++nt) { \
    floatx4 z = {BR[nt], BR[nt], BR[nt], BR[nt]}; acc[mt][nt] = z; } } while (0)

#define INIT_BIAS_RES(BR, RESBUF) do { \
  _Pragma("unroll") for (int mt = 0; mt < 4; ++mt) \
  _Pragma("unroll") for (int r = 0; r < 4; ++r) { \
    const int row = mt * 16 + quad * 4 + r; \
    const fp16x2 h2 = *(const fp16x2*)&RESBUF[row * ASTRIDE + col0]; \
    acc[mt][0][r] = BR[0] + (float)h2[0]; \
    acc[mt][1][r] = BR[1] + (float)h2[1]; \
  } } while (0)

#define GEMM128(SRC, MI) do { \
  _Pragma("unroll") for (int kq = 0; kq < 4; ++kq) { \
    half8 afr[4]; \
    _Pragma("unroll") for (int mt = 0; mt < 4; ++mt) \
      afr[mt] = *(const half8*)&SRC[(mt * 16 + l15) * ASTRIDE + kq * 32 + quad * 8]; \
    _Pragma("unroll") for (int mt = 0; mt < 4; ++mt) \
    _Pragma("unroll") for (int nt = 0; nt < 2; ++nt) \
      acc[mt][nt] = __builtin_amdgcn_mfma_f32_16x16x32_f16( \
          afr[mt], wfrag[MI][kq][nt], acc[mt][nt], 0, 0, 0); \
  } } while (0)

// pre_h0 GEMM (delta-free): runs inside the Wf phase, fills acc.
#define PRE_H0() do { \
  INIT_BIAS(b0r); \
  half8 afr0[4]; \
  _Pragma("unroll") for (int mt = 0; mt < 4; ++mt) \
    afr0[mt] = *(const half8*)&featb[(mt * 16 + l15) * FSTRIDE + quad * 8]; \
  _Pragma("unroll") for (int mt = 0; mt < 4; ++mt) \
  _Pragma("unroll") for (int nt = 0; nt < 2; ++nt) \
    acc[mt][nt] = __builtin_amdgcn_mfma_f32_16x16x32_f16( \
        afr0[mt], w0fragZ[nt], acc[mt][nt], 0, 0, 0); \
  } while (0)

// lrelu in f32, RTN casts, pack pair -> one b32 store
#define EPI_LRELU(DST) do { \
  _Pragma("unroll") for (int mt = 0; mt < 4; ++mt) \
  _Pragma("unroll") for (int r = 0; r < 4; ++r) { \
    const int row = mt * 16 + quad * 4 + r; \
    const float v0 = acc[mt][0][r]; \
    const float v1 = acc[mt][1][r]; \
    fp16x2 h2 = {(__fp16)fmaxf(v0, 0.2f * v0), (__fp16)fmaxf(v1, 0.2f * v1)}; \
    *(fp16x2*)&DST[row * ASTRIDE + col0] = h2; \
  } } while (0)

#define EPI_STORE(DST) do { \
  _Pragma("unroll") for (int mt = 0; mt < 4; ++mt) \
  _Pragma("unroll") for (int r = 0; r < 4; ++r) { \
    const int row = mt * 16 + quad * 4 + r; \
    fp16x2 h2 = {(__fp16)acc[mt][0][r], (__fp16)acc[mt][1][r]}; \
    *(fp16x2*)&DST[row * ASTRIDE + col0] = h2; \
  } } while (0)

  // Prologue: pre_h0 for step 0 (fr[3]=0 so W0Z == full W0 here).
  PRE_H0();

#pragma unroll 1
  for (int k = 0; k < NSTEPS; ++k) {
    // G0' (rank-1): acc holds pre_h0(k); add delta_{k-1}[row] * W0[3,col]
    // then lrelu. delta broadcast per row from featb[row,3] (u16, all l15
    // lanes same addr -> LDS broadcast, conflict-free).
    {
#pragma unroll
      for (int mt = 0; mt < 4; ++mt)
#pragma unroll
        for (int r = 0; r < 4; ++r) {
          const int row = mt * 16 + quad * 4 + r;
          const float dlt = (float)featb[row * FSTRIDE + 3];
          acc[mt][0][r] += dlt * w03[0];
          acc[mt][1][r] += dlt * w03[1];
        }
    }
    EPI_LRELU(bufA);
    __syncthreads();                                   // bar A: bufA ready

    // delta-independent features of step k+1 — overlaps the GEMM phase.
    // (Slds[.. k+1] valid at k=63: SLEN=65; write is dead then, harmless.)
    if (tid < ROWS) {
      const int kk = k + 1;
      const float lm = logf(Srow[kk] * 0.01f);
      const float rr = lm - lm_prev; qv += rr * rr;
      lm_prev = lm; cum_x += lm;
      const float tT = (float)kk * (1.f / 64.f);
      _Float16* fr = &featb[tid * FSTRIDE];
      fr[0] = (_Float16)lm;
      fr[1] = (_Float16)(1.f - tT);
      fr[4] = (_Float16)(cum_x / (float)(kk + 1));
      fr[5] = (_Float16)qv;
      fr[6] = (_Float16)(1.9f * sqrtf(qv + 1e-12f));
      fr[7] = (_Float16)tT;
    }

    INIT_BIAS(rb1r);            GEMM128(bufA, 0); EPI_LRELU(bufB);  // u
    __syncthreads();                                   // bar B: featb(k+1) stable
    INIT_BIAS_RES(rb2r, bufA);  GEMM128(bufB, 1); EPI_STORE(bufA);  // h1
    __syncthreads();                                   // bar C
    INIT_BIAS(sb1r);            GEMM128(bufA, 2); EPI_LRELU(bufB);  // v
    __syncthreads();                                   // bar D
    INIT_BIAS_RES(sb2r, bufA);  GEMM128(bufB, 3); EPI_STORE(bufA);  // h2
    __syncthreads();                                   // bar E: h2 in bufA

    // Wf phase: (a) delta = sigmoid(h2 @ Wf + bf) via broadcast-B MFMA;
    // (b) pre_h0 for step k+1 into acc (independent chain -> pipelines;
    // racing fr[3] writes hit a zero weight, f16 writes are atomic).
    {
      floatx4 dacc = {0.f, 0.f, 0.f, 0.f};
#pragma unroll
      for (int kq = 0; kq < 4; ++kq) {
        const half8 a  = *(const half8*)&bufA[(wave * 16 + l15) * ASTRIDE + kq * 32 + quad * 8];
        const half8 wv = *(const half8*)&WfS[kq * 32 + quad * 8];   // broadcast read
        dacc = __builtin_amdgcn_mfma_f32_16x16x32_f16(a, wv, dacc, 0, 0, 0);
      }
      PRE_H0();                                        // overlaps dacc chain
      if (l15 < 4) {
        // static-index select of dacc[l15] (rule: no runtime vector index)
        const float sv = (l15 & 2) ? ((l15 & 1) ? dacc[3] : dacc[2])
                                   : ((l15 & 1) ? dacc[1] : dacc[0]);
        const int row = wave * 16 + quad * 4 + l15;
        const float d = 1.f / (1.f + expf(-(sv + bfv)));
        featb[row * FSTRIDE + 3] = (_Float16)d;        // delta_k for G0'(k+1)
        deltab[row * DSTR + k] = d;                    // staged output
      }
    }
    __syncthreads();                                   // bar F: delta visible
  }

  // coalesced output flush: 64 rows x 64 steps, dwordx4 stores.
  // (bar F of k=63 made deltab fully visible.)
  {
    const int row = tid >> 2;                // 0..63
    const int c0  = (tid & 3) * 16;          // 0,16,32,48
    const float* dr = &deltab[row * DSTR + c0];
    float* orow = &out[(size_t)(r0 + row) * NSTEPS + c0];
#pragma unroll
    for (int u = 0; u < 4; ++u) {
      const floatx4 v = *(const floatx4*)&dr[u * 4];
      *(floatx4*)&orow[u * 4] = v;
    }
  }
#undef INIT_BIAS
#undef INIT_BIAS_RES
#undef GEMM128
#undef PRE_H0
#undef EPI_LRELU
#undef EPI_STORE
}

extern "C" void kernel_launch(void* const* d_in, const int* in_sizes, int n_in,
                              void* d_out, int out_size, void* d_ws, size_t ws_size,
                              hipStream_t stream) {
  const float* S   = (const float*)d_in[0];
  const float* W0  = (const float*)d_in[1];
  const float* b0  = (const float*)d_in[2];
  const float* rW1 = (const float*)d_in[3];
  const float* rb1 = (const float*)d_in[4];
  const float* rW2 = (const float*)d_in[5];
  const float* rb2 = (const float*)d_in[6];
  const float* sW1 = (const float*)d_in[7];
  const float* sb1 = (const float*)d_in[8];
  const float* sW2 = (const float*)d_in[9];
  const float* sb2 = (const float*)d_in[10];
  const float* Wf  = (const float*)d_in[11];
  const float* bf  = (const float*)d_in[12];
  float* out = (float*)d_out;

  const int B = out_size / NSTEPS;        // 32768
  const int nblocks = B / ROWS;           // 512 WGs -> 2 per CU
  hedger<<<nblocks, THREADS, 0, stream>>>(
      S, W0, b0, rW1, rb1, rW2, rb2, sW1, sb1, sW2, sb2, Wf, bf, out);
}

// Round 7
// 345.643 us; speedup vs baseline: 1.6211x; 1.2414x over previous
//
#include <hip/hip_runtime.h>
#include <math.h>

#define HID 128
#define NSTEPS 64
#define SLEN 65
#define THREADS 256
#define ROWS 64
#define ASTRIDE 136   // 128 + 8 f16 pad, 16B aligned rows
#define FSTRIDE 40    // 32 + 8 f16 pad
#define DSTR 68       // 64 + 4 f32 pad, 16B-aligned rows for b128 flush reads

typedef _Float16 half8 __attribute__((ext_vector_type(8)));
typedef __fp16 fp16x2 __attribute__((ext_vector_type(2)));
typedef float floatx4 __attribute__((ext_vector_type(4)));

// R19 = R13 structure with G4 DELETED algebraically (5 phases, 5 barriers).
// h2 is consumed ONLY by the Wf dot: h2 = h1 + v@sW2 + sb2, so
//   h2.Wf = h1.Wf + v.(sW2@Wf) + (sb2.Wf).
// Precompute ws2f = sW2@Wf (f16, init) and C = sb2.Wf + bf (scalar). The
// WF phase runs two independent broadcast-B MFMA chains (h1 from bufA,
// stable since bar C; v from bufB, stable since bar D) and sums selected
// scalars. Removes per step/wave: 32 MFMA + 16-value EPI + 16KB A-reads.
// wfrag shrinks 128->96 VGPR, sb2r dies -> pressure DOWN (R18's failure
// was +liveness across barriers -> spill WRITE+7.4MB; this has none).
// Numerics: swaps h2's f16 materialization error for ws2f's f16 rounding
// (same order); sigmoid contracts both.
// R13 kept: weights-in-VGPR, zero global ops in k-loop, staged coalesced
// flush, 16-lane sigmoid, feature-calc overlapped with G1.
// CLOSED: cols/wave != 32 (R3 spill; R16/R17 LDS traffic law: bytes ~
// 128/colsPerWave); min-waves>2 at this pressure (R15: FETCH 3.2GB);
// XOR swizzle (R14: conflict counter = structural b128 serialization,
// layout-invariant); acc live across barriers (R18 spill); 32x32 MFMA.
// VGPR_Count CSV lies about spill - watch FETCH/WRITE_SIZE.
__global__ __launch_bounds__(THREADS, 2)
void hedger(const float* __restrict__ S,
            const float* __restrict__ W0,  const float* __restrict__ b0,
            const float* __restrict__ rW1, const float* __restrict__ rb1,
            const float* __restrict__ rW2, const float* __restrict__ rb2,
            const float* __restrict__ sW1, const float* __restrict__ sb1,
            const float* __restrict__ sW2, const float* __restrict__ sb2,
            const float* __restrict__ Wf,  const float* __restrict__ bfp,
            float* __restrict__ out)
{
  __shared__ __align__(16) _Float16 bufA[ROWS * ASTRIDE];
  __shared__ __align__(16) _Float16 bufB[ROWS * ASTRIDE];
  __shared__ __align__(16) _Float16 featb[ROWS * FSTRIDE];
  __shared__ __align__(16) _Float16 WfS[HID];
  __shared__ __align__(16) _Float16 Ws2S[HID];   // ws2f = sW2 @ Wf
  __shared__             float    CvalS;         // sb2.Wf + bf
  __shared__ __align__(16) float    Slds[ROWS * SLEN];
  __shared__ __align__(16) float    deltab[ROWS * DSTR];

  const int tid  = threadIdx.x;
  const int wave = tid >> 6;            // 0..3
  const int lane = tid & 63;
  const int l15  = lane & 15;
  const int quad = lane >> 4;
  const int n_base = wave * 32;
  const int r0 = blockIdx.x * ROWS;
  const int col0 = n_base + 2 * l15;    // lane's adjacent column pair

  // ---- persistent B fragments (96 VGPR): rW1, rW2, sW1 only (sW2 folded).
  half8 wfrag[3][4][2];  // [matrix][kIter][nt]
  {
    const float* Wm[3] = {rW1, rW2, sW1};
#pragma unroll
    for (int m = 0; m < 3; ++m)
#pragma unroll
      for (int kq = 0; kq < 4; ++kq)
#pragma unroll
        for (int nt = 0; nt < 2; ++nt) {
          const int n  = col0 + nt;
          const int kb = kq * 32 + quad * 8;
          half8 f;
#pragma unroll
          for (int j = 0; j < 8; ++j)
            f[j] = (_Float16)Wm[m][(kb + j) * HID + n];
          wfrag[m][kq][nt] = f;
        }
  }
  // W0 (8x128) zero-padded to K=32: only quad 0 (k<8) is real.
  half8 w0frag[2];
#pragma unroll
  for (int nt = 0; nt < 2; ++nt) {
    const int n = col0 + nt;
    half8 f;
#pragma unroll
    for (int j = 0; j < 8; ++j) {
      const int k = quad * 8 + j;
      f[j] = (k < 8) ? (_Float16)W0[k * HID + n] : (_Float16)0.f;
    }
    w0frag[nt] = f;
  }
  // biases for this lane's columns (sb2 folded into Cval)
  float b0r[2], rb1r[2], rb2r[2], sb1r[2];
#pragma unroll
  for (int nt = 0; nt < 2; ++nt) {
    const int n = col0 + nt;
    b0r[nt] = b0[n]; rb1r[nt] = rb1[n]; rb2r[nt] = rb2[n]; sb1r[nt] = sb1[n];
  }

  // LDS zero-fill (pad cols 8..31 stay zero forever) + Wf + ws2f + Cval
  // + S staging.
  for (int i = tid; i < ROWS * FSTRIDE; i += THREADS) featb[i] = (_Float16)0.f;
  if (tid < HID) {
    WfS[tid] = (_Float16)Wf[tid];
    float s = 0.f;
    for (int n = 0; n < HID; ++n) s += sW2[tid * HID + n] * Wf[n];
    Ws2S[tid] = (_Float16)s;           // ws2f[k] = sum_n sW2[k,n]*Wf[n]
  }
  if (wave == 0) {                     // Cval = sb2.Wf + bf
    float p = sb2[lane] * Wf[lane] + sb2[lane + 64] * Wf[lane + 64];
    p += __shfl_xor(p, 1);  p += __shfl_xor(p, 2);  p += __shfl_xor(p, 4);
    p += __shfl_xor(p, 8);  p += __shfl_xor(p, 16); p += __shfl_xor(p, 32);
    if (lane == 0) CvalS = p + bfp[0];
  }
  for (int i = tid; i < ROWS * SLEN; i += THREADS)
    Slds[i] = S[(size_t)r0 * SLEN + i];       // contiguous, coalesced
  __syncthreads();   // init complete before feature writes
  const float Cval = CvalS;

  // step-0 features (threads 0..63 each own one row; S read from LDS)
  float lm_prev = 0.f, cum_x = 0.f, qv = 0.f;
  const float* Srow = &Slds[(tid & (ROWS - 1)) * SLEN];
  if (tid < ROWS) {
    const float lm = logf(Srow[0] * 0.01f);
    lm_prev = lm; cum_x = lm; qv = 0.f;
    _Float16* fr = &featb[tid * FSTRIDE];
    fr[0] = (_Float16)lm;
    fr[1] = (_Float16)1.0f;
    fr[2] = (_Float16)0.235f;
    fr[3] = (_Float16)0.f;                 // delta_0 = 0
    fr[4] = (_Float16)lm;                  // run_mean at k=0
    fr[5] = (_Float16)0.f;
    fr[6] = (_Float16)(1.9f * sqrtf(1e-12f));
    fr[7] = (_Float16)0.f;
  }
  __syncthreads();

  floatx4 acc[4][2];

#define INIT_BIAS(BR) do { \
  _Pragma("unroll") for (int mt = 0; mt < 4; ++mt) \
  _Pragma("unroll") for (int nt = 0; nt < 2; ++nt) { \
    floatx4 z = {BR[nt], BR[nt], BR[nt], BR[nt]}; acc[mt][nt] = z; } } while (0)

#define INIT_BIAS_RES(BR, RESBUF) do { \
  _Pragma("unroll") for (int mt = 0; mt < 4; ++mt) \
  _Pragma("unroll") for (int r = 0; r < 4; ++r) { \
    const int row = mt * 16 + quad * 4 + r; \
    const fp16x2 h2 = *(const fp16x2*)&RESBUF[row * ASTRIDE + col0]; \
    acc[mt][0][r] = BR[0] + (float)h2[0]; \
    acc[mt][1][r] = BR[1] + (float)h2[1]; \
  } } while (0)

#define GEMM128(SRC, MI) do { \
  _Pragma("unroll") for (int kq = 0; kq < 4; ++kq) { \
    half8 afr[4]; \
    _Pragma("unroll") for (int mt = 0; mt < 4; ++mt) \
      afr[mt] = *(const half8*)&SRC[(mt * 16 + l15) * ASTRIDE + kq * 32 + quad * 8]; \
    _Pragma("unroll") for (int mt = 0; mt < 4; ++mt) \
    _Pragma("unroll") for (int nt = 0; nt < 2; ++nt) \
      acc[mt][nt] = __builtin_amdgcn_mfma_f32_16x16x32_f16( \
          afr[mt], wfrag[MI][kq][nt], acc[mt][nt], 0, 0, 0); \
  } } while (0)

// lrelu in f32, RTN casts, pack pair -> one b32 store
#define EPI_LRELU(DST) do { \
  _Pragma("unroll") for (int mt = 0; mt < 4; ++mt) \
  _Pragma("unroll") for (int r = 0; r < 4; ++r) { \
    const int row = mt * 16 + quad * 4 + r; \
    const float v0 = acc[mt][0][r]; \
    const float v1 = acc[mt][1][r]; \
    fp16x2 h2 = {(__fp16)fmaxf(v0, 0.2f * v0), (__fp16)fmaxf(v1, 0.2f * v1)}; \
    *(fp16x2*)&DST[row * ASTRIDE + col0] = h2; \
  } } while (0)

#define EPI_STORE(DST) do { \
  _Pragma("unroll") for (int mt = 0; mt < 4; ++mt) \
  _Pragma("unroll") for (int r = 0; r < 4; ++r) { \
    const int row = mt * 16 + quad * 4 + r; \
    fp16x2 h2 = {(__fp16)acc[mt][0][r], (__fp16)acc[mt][1][r]}; \
    *(fp16x2*)&DST[row * ASTRIDE + col0] = h2; \
  } } while (0)

#pragma unroll 1
  for (int k = 0; k < NSTEPS; ++k) {
    // G0: h0 = lrelu(featPad @ W0pad + b0)   (featb complete via bar E)
    INIT_BIAS(b0r);
    {
      half8 afr[4];
#pragma unroll
      for (int mt = 0; mt < 4; ++mt)
        afr[mt] = *(const half8*)&featb[(mt * 16 + l15) * FSTRIDE + quad * 8];
#pragma unroll
      for (int mt = 0; mt < 4; ++mt)
#pragma unroll
        for (int nt = 0; nt < 2; ++nt)
          acc[mt][nt] = __builtin_amdgcn_mfma_f32_16x16x32_f16(
              afr[mt], w0frag[nt], acc[mt][nt], 0, 0, 0);
    }
    EPI_LRELU(bufA);
    __syncthreads();                                   // bar A: h0 in bufA

    // delta-independent features of step k+1 — overlaps the GEMM phase.
    // (Slds[.. k+1] valid at k=63: SLEN=65; write is dead then, harmless.)
    if (tid < ROWS) {
      const int kk = k + 1;
      const float lm = logf(Srow[kk] * 0.01f);
      const float rr = lm - lm_prev; qv += rr * rr;
      lm_prev = lm; cum_x += lm;
      const float tT = (float)kk * (1.f / 64.f);
      _Float16* fr = &featb[tid * FSTRIDE];
      fr[0] = (_Float16)lm;
      fr[1] = (_Float16)(1.f - tT);
      fr[4] = (_Float16)(cum_x / (float)(kk + 1));
      fr[5] = (_Float16)qv;
      fr[6] = (_Float16)(1.9f * sqrtf(qv + 1e-12f));
      fr[7] = (_Float16)tT;
    }

    INIT_BIAS(rb1r);            GEMM128(bufA, 0); EPI_LRELU(bufB);  // u
    __syncthreads();                                   // bar B
    INIT_BIAS_RES(rb2r, bufA);  GEMM128(bufB, 1); EPI_STORE(bufA);  // h1
    __syncthreads();                                   // bar C: h1 in bufA
    INIT_BIAS(sb1r);            GEMM128(bufA, 2); EPI_LRELU(bufB);  // v
    __syncthreads();                                   // bar D: v in bufB

    // WF: delta = sigmoid(h1.Wf + v.ws2f + Cval) via two independent
    // broadcast-B MFMA chains (h1 from bufA, v from bufB). G4 deleted.
    {
      floatx4 dacc  = {0.f, 0.f, 0.f, 0.f};
      floatx4 dacc2 = {0.f, 0.f, 0.f, 0.f};
#pragma unroll
      for (int kq = 0; kq < 4; ++kq) {
        const int off = kq * 32 + quad * 8;
        const half8 a1 = *(const half8*)&bufA[(wave * 16 + l15) * ASTRIDE + off];
        const half8 w1 = *(const half8*)&WfS[off];     // broadcast read
        dacc  = __builtin_amdgcn_mfma_f32_16x16x32_f16(a1, w1, dacc, 0, 0, 0);
        const half8 a2 = *(const half8*)&bufB[(wave * 16 + l15) * ASTRIDE + off];
        const half8 w2 = *(const half8*)&Ws2S[off];    // broadcast read
        dacc2 = __builtin_amdgcn_mfma_f32_16x16x32_f16(a2, w2, dacc2, 0, 0, 0);
      }
      if (l15 < 4) {
        // static-index select (rule: no runtime vector index)
        const float s1 = (l15 & 2) ? ((l15 & 1) ? dacc[3] : dacc[2])
                                   : ((l15 & 1) ? dacc[1] : dacc[0]);
        const float s2 = (l15 & 2) ? ((l15 & 1) ? dacc2[3] : dacc2[2])
                                   : ((l15 & 1) ? dacc2[1] : dacc2[0]);
        const int row = wave * 16 + quad * 4 + l15;
        const float d = 1.f / (1.f + expf(-(s1 + s2 + Cval)));
        featb[row * FSTRIDE + 3] = (_Float16)d;        // fr[3] for step k+1
        deltab[row * DSTR + k] = d;                    // staged output
      }
    }
    __syncthreads();                                   // bar E: featb complete
  }

  // coalesced output flush: 64 rows x 64 steps, dwordx4 stores.
  // (bar E of k=63 made deltab fully visible.)
  {
    const int row = tid >> 2;                // 0..63
    const int c0  = (tid & 3) * 16;          // 0,16,32,48
    const float* dr = &deltab[row * DSTR + c0];
    float* orow = &out[(size_t)(r0 + row) * NSTEPS + c0];
#pragma unroll
    for (int u = 0; u < 4; ++u) {
      const floatx4 v = *(const floatx4*)&dr[u * 4];
      *(floatx4*)&orow[u * 4] = v;
    }
  }
#undef INIT_BIAS
#undef INIT_BIAS_RES
#undef GEMM128
#undef EPI_LRELU
#undef EPI_STORE
}

extern "C" void kernel_launch(void* const* d_in, const int* in_sizes, int n_in,
                              void* d_out, int out_size, void* d_ws, size_t ws_size,
                              hipStream_t stream) {
  const float* S   = (const float*)d_in[0];
  const float* W0  = (const float*)d_in[1];
  const float* b0  = (const float*)d_in[2];
  const float* rW1 = (const float*)d_in[3];
  const float* rb1 = (const float*)d_in[4];
  const float* rW2 = (const float*)d_in[5];
  const float* rb2 = (const float*)d_in[6];
  const float* sW1 = (const float*)d_in[7];
  const float* sb1 = (const float*)d_in[8];
  const float* sW2 = (const float*)d_in[9];
  const float* sb2 = (const float*)d_in[10];
  const float* Wf  = (const float*)d_in[11];
  const float* bf  = (const float*)d_in[12];
  float* out = (float*)d_out;

  const int B = out_size / NSTEPS;        // 32768
  const int nblocks = B / ROWS;           // 512 WGs -> 2 per CU
  hedger<<<nblocks, THREADS, 0, stream>>>(
      S, W0, b0, rW1, rb1, rW2, rb2, sW1, sb1, sW2, sb2, Wf, bf, out);
}